// Round 12
// baseline (293.649 us; speedup 1.0000x reference)
//
#include <hip/hip_runtime.h>
#include <stdint.h>

#define NCLASS 41
#define TLEN   1024
#define NBATCH 1024
// per-batch backpointer stride: (TLEN-1)*NCLASS = 41943, round to mult of 8
#define BP_STRIDE 41944
#define NTRANS (NCLASS * NCLASS)
#define NEGINF (-3.0e38f)
#define MASK41 ((1ull << NCLASS) - 1)

#define RDLANE(v, l) __int_as_float(__builtin_amdgcn_readlane(__float_as_int(v), (l)))

// Full-wave max + broadcast via DPP (value only; used at init).
__device__ __forceinline__ float wave_max_bcast(float x) {
    int xi = __float_as_int(x);
    int t;
    t = __builtin_amdgcn_update_dpp(xi, xi, 0x111, 0xf, 0xf, false);
    x = fmaxf(x, __int_as_float(t)); xi = __float_as_int(x);
    t = __builtin_amdgcn_update_dpp(xi, xi, 0x112, 0xf, 0xf, false);
    x = fmaxf(x, __int_as_float(t)); xi = __float_as_int(x);
    t = __builtin_amdgcn_update_dpp(xi, xi, 0x114, 0xf, 0xf, false);
    x = fmaxf(x, __int_as_float(t)); xi = __float_as_int(x);
    t = __builtin_amdgcn_update_dpp(xi, xi, 0x118, 0xf, 0xf, false);
    x = fmaxf(x, __int_as_float(t)); xi = __float_as_int(x);
    t = __builtin_amdgcn_update_dpp(xi, xi, 0x142, 0xf, 0xf, false);
    x = fmaxf(x, __int_as_float(t)); xi = __float_as_int(x);
    t = __builtin_amdgcn_update_dpp(xi, xi, 0x143, 0xf, 0xf, false);
    x = fmaxf(x, __int_as_float(t));
    return __int_as_float(__builtin_amdgcn_readlane(__float_as_int(x), 63));
}

// Dual (value,index) DPP argmax level. "Shifted wins ties" (>=): shifted
// data always originates from LOWER original lanes in this shr/bcast
// pattern, so the final lane-63 aggregate carries the MIN index among all
// maxima — first-index argmax semantics. Invalid lanes keep old (self):
// vf_ == v -> take self index. All VALU (vcc-coupled), no SALU round trips.
#define ARGMAX_LVL(ctrl) {                                                    \
        int vs_ = __builtin_amdgcn_update_dpp(                                \
            __float_as_int(v_), __float_as_int(v_), ctrl, 0xf, 0xf, false);   \
        int is_ = __builtin_amdgcn_update_dpp(id_, id_, ctrl, 0xf, 0xf, false);\
        float vf_ = __int_as_float(vs_);                                      \
        bool tk_ = (vf_ >= v_);                                               \
        v_  = tk_ ? vf_ : v_;                                                 \
        id_ = tk_ ? is_ : id_;                                                \
    }
#define ARGMAX_TREE() ARGMAX_LVL(0x111) ARGMAX_LVL(0x112) ARGMAX_LVL(0x114)   \
                      ARGMAX_LVL(0x118) ARGMAX_LVL(0x142) ARGMAX_LVL(0x143)

// ---------------------------------------------------------------------------
// Viterbi forward. Dual DPP argmax tree (value+index, min-index ties) gives
// M and i1 with NO ballot/ffs/readlane SALU round trips on the common path.
// cnt==1 (~75%): winner for every column is i1 (unique max; any exact max
// tie implies cnt>=2). ds_read of row i1 issues right after one readlane;
// the ballot (competitor check) runs in its shadow and gates a uniform
// branch. cnt>=2 (~25%): round-11's exact ascending 2/4-wide peel + serial.
// Rationale (r11 counters): 605cy/step at only ~175cy VALU issue -> the
// stalls are VALU<->SALU pipeline crossings; remove them from the chain.
// ---------------------------------------------------------------------------
__global__ __launch_bounds__(64, 1) void crf_forward(
    const float* __restrict__ x,        // [B, T, C]
    const float* __restrict__ start_t,  // [C]
    const float* __restrict__ end_t,    // [C]
    const float* __restrict__ trans,    // [C, C]
    uint8_t* __restrict__ bp,           // [B, BP_STRIDE]
    int* __restrict__ out)              // [B, T]
{
    __shared__ float tl[NTRANS + 32];   // trans rows; pad so reads never OOB

    const int b = blockIdx.x;
    const int j = threadIdx.x;
    const int jc = (j < NCLASS) ? j : (NCLASS - 1);  // mirror lanes 41..63

    // Stage trans into LDS; D = max - min (exact, from data)
    float mx = NEGINF, mn = 3.0e38f;
    for (int k = j; k < NTRANS; k += 64) {
        float v = trans[k];
        tl[k] = v;
        mx = fmaxf(mx, v);
        mn = fminf(mn, v);
    }
    __syncthreads();
    const float Dmax = wave_max_bcast(mx);
    const float Dmin = -wave_max_bcast(-mn);
    const float D = Dmax - Dmin;

    const float* xb = x + (size_t)b * TLEN * NCLASS;
    uint8_t* bpb = bp + (size_t)b * BP_STRIDE;

    // All lanes live: lanes 41-63 mirror lane 40 (same loads, same values).
    float score = start_t[jc] + xb[jc];

    auto step = [&](float e, int boff) {
        // Dual argmax tree on current score (on-chain, pure VALU).
        float v_ = score; int id_ = j;
        ARGMAX_TREE();
        float M  = RDLANE(v_, 63);
        int   i1 = __builtin_amdgcn_readlane(id_, 63);   // min-index argmax
        float t1 = tl[i1 * NCLASS + jc];                 // ds_read, issues early
        unsigned long long me = __ballot(score >= M - D) & MASK41;
        if (__builtin_expect(me == (1ull << i1), 1)) {
            // Unique candidate: winner of every column is i1.
            bpb[boff] = (uint8_t)i1;
            score = (M + t1) + e;
        } else {
            // cnt >= 2: exact ascending peel (round-11 path, verbatim).
            int cnt = __popcll(me);
            int a1 = __ffsll(me) - 1;
            int a2 = 63 - __clzll(me);
            float s1 = RDLANE(score, a1);
            float s2 = RDLANE(score, a2);
            float u1 = s1 + tl[a1 * NCLASS + jc];
            float u2 = s2 + tl[a2 * NCLASS + jc];
            bool c = u2 > u1;                    // a1 < a2: strict > keeps
            float best = c ? u2 : u1;            //   first-index semantics
            int bidx = c ? a2 : a1;
            if (__builtin_expect(cnt >= 3, 0)) {
                unsigned long long mr = me & ~((1ull << a1) | (1ull << a2));
                if (__builtin_expect(cnt <= 4, 1)) {
                    int a3 = __ffsll(mr) - 1;
                    int a4 = 63 - __clzll(mr);   // == a3 when cnt == 3
                    float s3 = RDLANE(score, a3);
                    float s4 = RDLANE(score, a4);
                    float u3 = s3 + tl[a3 * NCLASS + jc];
                    float u4 = s4 + tl[a4 * NCLASS + jc];
                    // ascending merge order: a1 < a3 <= a4 < a2
                    best = u1; bidx = a1;
                    if (u3 > best) { best = u3; bidx = a3; }
                    if (u4 > best) { best = u4; bidx = a4; }
                    if (u2 > best) { best = u2; bidx = a2; }
                } else {                          // cnt >= 5: exact serial
                    best = NEGINF; bidx = 0;
                    unsigned long long mm = me;
                    while (mm) {
                        int ic = __ffsll(mm) - 1; mm &= mm - 1;
                        float sc = RDLANE(score, ic);
                        float vc = sc + tl[ic * NCLASS + jc];
                        if (vc > best) { best = vc; bidx = ic; }
                    }
                }
            }
            bpb[boff] = (uint8_t)bidx;
            score = best + e;
        }
    };

    // Rolling 4-deep emission prefetch, 32-bit offsets (SGPR base + voffset).
    int eoff = 1 * NCLASS + jc;          // element offset of em row 1
    float e0 = xb[eoff];
    float e1 = xb[eoff + NCLASS];
    float e2 = xb[eoff + 2 * NCLASS];
    float e3 = xb[eoff + 3 * NCLASS];
    eoff += 4 * NCLASS;                  // -> row t0+4 while t0 is current
    int boff = jc;                       // bp offset for t = 1

    // Main loop: steps 1..1016 (reloads rows t0+4..t0+7 <= 1020: never OOB)
    int t0 = 1;
    for (; t0 + 7 <= TLEN - 4; t0 += 4) {
        step(e0, boff);              e0 = xb[eoff];
        step(e1, boff + NCLASS);     e1 = xb[eoff + NCLASS];
        step(e2, boff + 2 * NCLASS); e2 = xb[eoff + 2 * NCLASS];
        step(e3, boff + 3 * NCLASS); e3 = xb[eoff + 3 * NCLASS];
        eoff += 4 * NCLASS;
        boff += 4 * NCLASS;
    }
    // Tail: t0 == 1017; e0..e3 hold rows 1017..1020. Steps 1017..1020 with
    // reloads of rows 1021..1023 (no OOB), then steps 1021..1023.
    step(e0, boff);              e0 = xb[eoff];               // row 1021
    step(e1, boff + NCLASS);     e1 = xb[eoff + NCLASS];      // row 1022
    step(e2, boff + 2 * NCLASS); e2 = xb[eoff + 2 * NCLASS];  // row 1023
    step(e3, boff + 3 * NCLASS);
    boff += 4 * NCLASS;
    step(e0, boff);
    step(e1, boff + NCLASS);
    step(e2, boff + 2 * NCLASS);

    // Final: add end transitions; first-index argmax via the dual tree.
    // Mirror lanes tie with lane 40 -> min-index picks <= 40.
    {
        float v_ = score + end_t[jc]; int id_ = j;
        ARGMAX_TREE();
        int idx = __builtin_amdgcn_readlane(id_, 63);
        if (j == 0) out[(size_t)b * TLEN + (TLEN - 1)] = idx;
    }
}

// ---------------------------------------------------------------------------
// Kernel B: backtracking (unchanged; measured cheap).
// ---------------------------------------------------------------------------
__global__ __launch_bounds__(1024) void crf_backtrack(
    const uint8_t* __restrict__ bp,
    int* __restrict__ out)
{
    __shared__ uint8_t bpl[BP_STRIDE];     // 41944 B
    __shared__ int maps[16][NCLASS];       // chunk boundary maps
    __shared__ int entry[16];              // true tag at each chunk end

    const int b = blockIdx.x;
    const int tid = threadIdx.x;
    const int w = tid >> 6;
    const int lane = tid & 63;

    {
        const uint32_t* src = (const uint32_t*)(bp + (size_t)b * BP_STRIDE);
        uint32_t* dst = (uint32_t*)bpl;
        for (int i = tid; i < BP_STRIDE / 4; i += 1024) dst[i] = src[i];
    }
    __syncthreads();

    const int cs = w * 64;
    const int ce = min(cs + 64, TLEN - 1);  // last chunk: 63 columns
    const int L = ce - cs;

    // Phase 1: hypothesis walk for all 41 entering tags (lane = hypothesis)
    {
        int xx = (lane < NCLASS) ? lane : 0;
        for (int t = ce; t > cs; --t)
            xx = bpl[(t - 1) * NCLASS + xx];
        if (lane < NCLASS) maps[w][lane] = xx;
    }
    __syncthreads();

    // Stitch chunk boundaries serially on one thread
    if (tid == 0) {
        int cur = out[(size_t)b * TLEN + (TLEN - 1)];  // tag @ T-1 from fwd
        for (int ww = 15; ww >= 0; --ww) {
            entry[ww] = cur;
            cur = maps[ww][cur];
        }
    }
    __syncthreads();

    // Phase 2: replay with true entering tag; lane l captures step l's tag
    {
        int xx = entry[w];
        int cap = 0;
        for (int k = 0; k < L; ++k) {
            xx = bpl[(ce - 1 - k) * NCLASS + xx];
            if (k == lane) cap = xx;
        }
        if (lane < L) out[(size_t)b * TLEN + (ce - 1 - lane)] = cap;
    }
}

// ---------------------------------------------------------------------------
extern "C" void kernel_launch(void* const* d_in, const int* in_sizes, int n_in,
                              void* d_out, int out_size, void* d_ws, size_t ws_size,
                              hipStream_t stream) {
    const float* x       = (const float*)d_in[0];
    const float* start_t = (const float*)d_in[1];
    const float* end_t   = (const float*)d_in[2];
    const float* trans   = (const float*)d_in[3];
    int* out = (int*)d_out;
    uint8_t* bp = (uint8_t*)d_ws;  // needs NBATCH * BP_STRIDE = ~42.9 MB

    crf_forward<<<NBATCH, 64, 0, stream>>>(x, start_t, end_t, trans, bp, out);
    crf_backtrack<<<NBATCH, 1024, 0, stream>>>(bp, out);
}